// Round 4
// baseline (58.942 us; speedup 1.0000x reference)
//
#include <hip/hip_runtime.h>
#include <hip/hip_cooperative_groups.h>

namespace cg = cooperative_groups;

#define TILE 256
#define NBLK 512
#define DELTA 10.0f

// Single fused cooperative kernel.
// Encoding trick: u_i = x if pos else -1e30 ; v_j = y if neg else +1e30.
// (u_i > v_j) counts exactly (pos,neg) pairs with x > y.
// Hinge-clip correction: xx_i = 10+x if pos else +1e30 ; w_j = y if neg
// else -1e30 ; dm = min(xx-w, 0) nonzero only for clipping (pos,neg) pairs.
// Closed form: sum max(10+x-y,0)^2 over (pos,neg) = Nn*A2 - 2*A1*S1 + P*S2 - corr.
__global__ void __launch_bounds__(256, 2)
fused_kernel(const float* __restrict__ pred, const int* __restrict__ target,
             int B, int nTj, int nT,
             double* __restrict__ part, float* __restrict__ out) {
    __shared__ float vsh[TILE];
    __shared__ float wsh[TILE];
    __shared__ float smaxs[4];
    __shared__ double sred[4][8];

    const int tid = threadIdx.x;
    const int bid = blockIdx.x;

    // ---- Phase 0: O(B) double-precision moment partials ----
    double a1 = 0, a2 = 0, s1 = 0, s2 = 0, Pc = 0, Nc = 0;
    for (int i = bid * 256 + tid; i < B; i += NBLK * 256) {
        const double x = (double)pred[i];
        const int t = target[i];
        if (t == 1) { const double z = 10.0 + x; a1 += z; a2 += z * z; Pc += 1.0; }
        else if (t == 0) { s1 += x; s2 += x * x; Nc += 1.0; }
    }

    // ---- Phase 1: pairwise tiles (grid-stride over nT tiles) ----
    unsigned tc = 0;
    float corr = 0.0f;
    for (int t = bid; t < nT; t += NBLK) {
        const int bi = t / nTj;
        const int bj = t % nTj;
        __syncthreads();  // protect vsh/wsh across tiles
        const int jg = bj * TILE + tid;
        float vj = 1e30f, wj = -1e30f;
        if (jg < B) {
            const float y = pred[jg];
            if (target[jg] == 0) { vj = y; wj = y; }
        }
        vsh[tid] = vj;
        wsh[tid] = wj;
        float wmax = wj;
        #pragma unroll
        for (int off = 32; off > 0; off >>= 1)
            wmax = fmaxf(wmax, __shfl_xor(wmax, off));
        if ((tid & 63) == 0) smaxs[tid >> 6] = wmax;
        __syncthreads();
        const float tileMax = fmaxf(fmaxf(smaxs[0], smaxs[1]),
                                    fmaxf(smaxs[2], smaxs[3]));

        const int ig = bi * TILE + tid;
        float u = -1e30f, xx = 1e30f;
        if (ig < B) {
            const float x = pred[ig];
            if (target[ig] == 1) { u = x; xx = DELTA + x; }
        }
        const float4* v4 = (const float4*)vsh;
        if (__all(xx >= tileMax)) {
            // fast path: no pair in this (wave, tile) can clip the hinge
            #pragma unroll 8
            for (int jj = 0; jj < TILE / 4; ++jj) {
                const float4 vv = v4[jj];
                tc += (u > vv.x);
                tc += (u > vv.y);
                tc += (u > vv.z);
                tc += (u > vv.w);
            }
        } else {
            const float4* w4 = (const float4*)wsh;
            #pragma unroll 4
            for (int jj = 0; jj < TILE / 4; ++jj) {
                const float4 vv = v4[jj];
                const float4 ww = w4[jj];
                float dm;
                tc += (u > vv.x); dm = fminf(xx - ww.x, 0.0f); corr = fmaf(dm, dm, corr);
                tc += (u > vv.y); dm = fminf(xx - ww.y, 0.0f); corr = fmaf(dm, dm, corr);
                tc += (u > vv.z); dm = fminf(xx - ww.z, 0.0f); corr = fmaf(dm, dm, corr);
                tc += (u > vv.w); dm = fminf(xx - ww.w, 0.0f); corr = fmaf(dm, dm, corr);
            }
        }
    }

    // ---- Block reduction of 8 quantities (fixed order, deterministic) ----
    double q[8] = {(double)tc, (double)corr, a1, a2, s1, s2, Pc, Nc};
    #pragma unroll
    for (int off = 32; off > 0; off >>= 1) {
        #pragma unroll
        for (int a = 0; a < 8; ++a) q[a] += __shfl_xor(q[a], off);
    }
    __syncthreads();
    if ((tid & 63) == 0) {
        #pragma unroll
        for (int a = 0; a < 8; ++a) sred[tid >> 6][a] = q[a];
    }
    __syncthreads();
    if (tid == 0) {
        #pragma unroll
        for (int a = 0; a < 8; ++a)
            part[bid * 8 + a] = sred[0][a] + sred[1][a] + sred[2][a] + sred[3][a];
    }

    cg::this_grid().sync();

    // ---- Phase 2: block 0 final reduce + combine ----
    if (bid == 0) {
        double r[8] = {0, 0, 0, 0, 0, 0, 0, 0};
        for (int row = tid; row < NBLK; row += 256) {
            #pragma unroll
            for (int a = 0; a < 8; ++a) r[a] += part[row * 8 + a];
        }
        #pragma unroll
        for (int off = 32; off > 0; off >>= 1) {
            #pragma unroll
            for (int a = 0; a < 8; ++a) r[a] += __shfl_xor(r[a], off);
        }
        __syncthreads();
        if ((tid & 63) == 0) {
            #pragma unroll
            for (int a = 0; a < 8; ++a) sred[tid >> 6][a] = r[a];
        }
        __syncthreads();
        if (tid == 0) {
            double f[8];
            #pragma unroll
            for (int a = 0; a < 8; ++a)
                f[a] = sred[0][a] + sred[1][a] + sred[2][a] + sred[3][a];
            const double P = f[6], Nn = f[7];
            const double lossSum = Nn * f[3] - 2.0 * f[2] * f[4] + P * f[5] - f[1];
            const double Np = P * Nn;
            out[0] = (float)(lossSum / Np);
            out[1] = (float)(f[0] / Np);
        }
    }
}

extern "C" void kernel_launch(void* const* d_in, const int* in_sizes, int n_in,
                              void* d_out, int out_size, void* d_ws, size_t ws_size,
                              hipStream_t stream) {
    const float* pred = (const float*)d_in[0];
    const int* target = (const int*)d_in[1];
    int B = in_sizes[0];

    int nTj = (B + TILE - 1) / TILE;
    int nT = nTj * nTj;
    double* part = (double*)d_ws;   // NBLK * 8 doubles = 32 KB
    float* out = (float*)d_out;

    void* args[] = {(void*)&pred, (void*)&target, (void*)&B, (void*)&nTj,
                    (void*)&nT, (void*)&part, (void*)&out};
    hipLaunchCooperativeKernel((const void*)fused_kernel, dim3(NBLK), dim3(256),
                               args, 0, stream);
}

// Round 5
// 30.100 us; speedup vs baseline: 1.9582x; 1.9582x over previous
//
#include <hip/hip_runtime.h>

#define TILE 256
#define NBLK 512
#define DELTA 10.0f
#define MAGIC 0x13579BDFu

// Single ordinary dispatch. Encoding trick: u_i = x if pos else -1e30 ;
// v_j = y if neg else +1e30 ; (u_i > v_j) counts exactly (pos,neg) pairs
// with x > y. Hinge-clip correction: xx_i = 10+x if pos else +1e30 ;
// w_j = y if neg else -1e30 ; dm = min(xx-w,0) nonzero only for clipping
// (pos,neg) pairs. Closed form:
//   sum max(10+x-y,0)^2 over (pos,neg) = Nn*A2 - 2*A1*S1 + P*S2 - corr.
// Last-block finalize via device-scope release/acquire flags (no grid.sync).
// 512 blocks x 256 thr x 32 VGPR x 2.5KB LDS: all co-resident (2 blocks/CU),
// so block 0's bounded spin cannot deadlock.
__global__ void __launch_bounds__(256)
fused_kernel(const float* __restrict__ pred, const int* __restrict__ target,
             int B, int nTj, int nT,
             double* __restrict__ part, unsigned* __restrict__ flag,
             float* __restrict__ out) {
    __shared__ float vsh[TILE];
    __shared__ float wsh[TILE];
    __shared__ float smaxs[4];
    __shared__ double sred[4][8];

    const int tid = threadIdx.x;
    const int bid = blockIdx.x;

    // ---- Phase 0: O(B) double-precision moment partials (slice) ----
    double a1 = 0, a2 = 0, s1 = 0, s2 = 0, Pc = 0, Nc = 0;
    for (int i = bid * 256 + tid; i < B; i += NBLK * 256) {
        const double x = (double)pred[i];
        const int t = target[i];
        if (t == 1) { const double z = 10.0 + x; a1 += z; a2 += z * z; Pc += 1.0; }
        else if (t == 0) { s1 += x; s2 += x * x; Nc += 1.0; }
    }

    // ---- Phase 1: pairwise tiles (grid-stride, nT/NBLK = 2 tiles/block) ----
    unsigned tc = 0;
    float corr = 0.0f;
    for (int t = bid; t < nT; t += NBLK) {
        const int bi = t / nTj;
        const int bj = t % nTj;
        __syncthreads();  // protect vsh/wsh across tiles
        const int jg = bj * TILE + tid;
        float vj = 1e30f, wj = -1e30f;
        if (jg < B) {
            const float y = pred[jg];
            if (target[jg] == 0) { vj = y; wj = y; }
        }
        vsh[tid] = vj;
        wsh[tid] = wj;
        float wmax = wj;
        #pragma unroll
        for (int off = 32; off > 0; off >>= 1)
            wmax = fmaxf(wmax, __shfl_xor(wmax, off));
        if ((tid & 63) == 0) smaxs[tid >> 6] = wmax;
        __syncthreads();
        const float tileMax = fmaxf(fmaxf(smaxs[0], smaxs[1]),
                                    fmaxf(smaxs[2], smaxs[3]));

        const int ig = bi * TILE + tid;
        float u = -1e30f, xx = 1e30f;
        if (ig < B) {
            const float x = pred[ig];
            if (target[ig] == 1) { u = x; xx = DELTA + x; }
        }
        const float4* v4 = (const float4*)vsh;
        if (__all(xx >= tileMax)) {
            // fast path: no pair in this (wave, tile) can clip the hinge
            #pragma unroll 8
            for (int jj = 0; jj < TILE / 4; ++jj) {
                const float4 vv = v4[jj];
                tc += (u > vv.x);
                tc += (u > vv.y);
                tc += (u > vv.z);
                tc += (u > vv.w);
            }
        } else {
            const float4* w4 = (const float4*)wsh;
            #pragma unroll 4
            for (int jj = 0; jj < TILE / 4; ++jj) {
                const float4 vv = v4[jj];
                const float4 ww = w4[jj];
                float dm;
                tc += (u > vv.x); dm = fminf(xx - ww.x, 0.0f); corr = fmaf(dm, dm, corr);
                tc += (u > vv.y); dm = fminf(xx - ww.y, 0.0f); corr = fmaf(dm, dm, corr);
                tc += (u > vv.z); dm = fminf(xx - ww.z, 0.0f); corr = fmaf(dm, dm, corr);
                tc += (u > vv.w); dm = fminf(xx - ww.w, 0.0f); corr = fmaf(dm, dm, corr);
            }
        }
    }

    // ---- Block reduction of 8 quantities (fixed order, deterministic) ----
    double q[8] = {(double)tc, (double)corr, a1, a2, s1, s2, Pc, Nc};
    #pragma unroll
    for (int off = 32; off > 0; off >>= 1) {
        #pragma unroll
        for (int a = 0; a < 8; ++a) q[a] += __shfl_xor(q[a], off);
    }
    __syncthreads();
    if ((tid & 63) == 0) {
        #pragma unroll
        for (int a = 0; a < 8; ++a) sred[tid >> 6][a] = q[a];
    }
    __syncthreads();
    if (tid == 0) {
        #pragma unroll
        for (int a = 0; a < 8; ++a)
            part[bid * 8 + a] = sred[0][a] + sred[1][a] + sred[2][a] + sred[3][a];
        __threadfence();  // make partials visible at device scope
        __hip_atomic_store(&flag[bid], MAGIC, __ATOMIC_RELEASE,
                           __HIP_MEMORY_SCOPE_AGENT);
    }

    // ---- Block 0: wait for all partials, reduce, emit, reset flags ----
    if (bid == 0) {
        for (int b = tid; b < NBLK; b += 256) {
            while (__hip_atomic_load(&flag[b], __ATOMIC_ACQUIRE,
                                     __HIP_MEMORY_SCOPE_AGENT) != MAGIC) {
                __builtin_amdgcn_s_sleep(1);
            }
        }
        __syncthreads();
        double r[8] = {0, 0, 0, 0, 0, 0, 0, 0};
        for (int row = tid; row < NBLK; row += 256) {
            #pragma unroll
            for (int a = 0; a < 8; ++a)
                r[a] += __hip_atomic_load(&part[row * 8 + a], __ATOMIC_RELAXED,
                                          __HIP_MEMORY_SCOPE_AGENT);
        }
        #pragma unroll
        for (int off = 32; off > 0; off >>= 1) {
            #pragma unroll
            for (int a = 0; a < 8; ++a) r[a] += __shfl_xor(r[a], off);
        }
        __syncthreads();
        if ((tid & 63) == 0) {
            #pragma unroll
            for (int a = 0; a < 8; ++a) sred[tid >> 6][a] = r[a];
        }
        __syncthreads();
        if (tid == 0) {
            double f[8];
            #pragma unroll
            for (int a = 0; a < 8; ++a)
                f[a] = sred[0][a] + sred[1][a] + sred[2][a] + sred[3][a];
            const double P = f[6], Nn = f[7];
            const double lossSum = Nn * f[3] - 2.0 * f[2] * f[4] + P * f[5] - f[1];
            const double Np = P * Nn;
            out[0] = (float)(lossSum / Np);
            out[1] = (float)(f[0] / Np);
        }
        __syncthreads();
        // reset flags so every call (and every graph replay) starts clean
        for (int b = tid; b < NBLK; b += 256)
            __hip_atomic_store(&flag[b], 0u, __ATOMIC_RELAXED,
                               __HIP_MEMORY_SCOPE_AGENT);
    }
}

extern "C" void kernel_launch(void* const* d_in, const int* in_sizes, int n_in,
                              void* d_out, int out_size, void* d_ws, size_t ws_size,
                              hipStream_t stream) {
    const float* pred = (const float*)d_in[0];
    const int* target = (const int*)d_in[1];
    const int B = in_sizes[0];

    const int nTj = (B + TILE - 1) / TILE;
    const int nT = nTj * nTj;

    double* part   = (double*)d_ws;                       // NBLK*8 doubles = 32 KB
    unsigned* flag = (unsigned*)((char*)d_ws + NBLK * 8 * sizeof(double));

    fused_kernel<<<NBLK, 256, 0, stream>>>(pred, target, B, nTj, nT,
                                           part, flag, (float*)d_out);
}